// Round 1
// baseline (811.485 us; speedup 1.0000x reference)
//
#include <hip/hip_runtime.h>

#define NN   100000
#define NE   1600000
#define FEAT 128
#define HID  64
#define OUTD 40

// ---- degree: deg[i] = #edges with dst==i (float; exact for counts < 2^24) ----
__global__ __launch_bounds__(256) void k_deg(const int* __restrict__ dst,
                                             float* __restrict__ deg) {
    int e = blockIdx.x * 256 + threadIdx.x;
    if (e < NE) atomicAdd(&deg[dst[e]], 1.0f);
}

// ---- dinv[i] = rsqrt(deg+1), in place ----
__global__ __launch_bounds__(256) void k_dinv(float* __restrict__ deg) {
    int i = blockIdx.x * 256 + threadIdx.x;
    if (i < NN) deg[i] = rsqrtf(deg[i] + 1.0f);
}

// ---- h1 = x @ W1 : [NN,128] @ [128,64]  (16 rows per 256-thread block) ----
__global__ __launch_bounds__(256) void k_gemm1(const float* __restrict__ x,
                                               const float* __restrict__ W1,
                                               float* __restrict__ h1) {
    __shared__ float sW[FEAT * HID];   // 32 KB
    __shared__ float sX[16 * FEAT];    // 8 KB
    int t = threadIdx.x;
    for (int i = t; i < FEAT * HID; i += 256) sW[i] = W1[i];
    long row0 = (long)blockIdx.x * 16;
    for (int i = t; i < 16 * FEAT; i += 256) {
        long r = row0 + (i >> 7);
        sX[i] = (r < NN) ? x[r * FEAT + (i & 127)] : 0.f;
    }
    __syncthreads();
    int c  = t & 63;
    int rg = t >> 6;                   // 0..3, wave-uniform
    float s0 = 0.f, s1 = 0.f, s2 = 0.f, s3 = 0.f;
    #pragma unroll 8
    for (int k = 0; k < FEAT; ++k) {
        float w = sW[k * HID + c];
        s0 = fmaf(sX[(rg * 4 + 0) * FEAT + k], w, s0);
        s1 = fmaf(sX[(rg * 4 + 1) * FEAT + k], w, s1);
        s2 = fmaf(sX[(rg * 4 + 2) * FEAT + k], w, s2);
        s3 = fmaf(sX[(rg * 4 + 3) * FEAT + k], w, s3);
    }
    float sv[4] = {s0, s1, s2, s3};
    #pragma unroll
    for (int j = 0; j < 4; ++j) {
        long row = row0 + rg * 4 + j;
        if (row < NN) h1[row * HID + c] = sv[j];
    }
}

// ---- scatter conv1: agg[dst] += h1[src] * dinv[src]*dinv[dst]  (1 wave = 1 edge) ----
__global__ __launch_bounds__(256) void k_scatter1(const int* __restrict__ src,
                                                  const int* __restrict__ dst,
                                                  const float* __restrict__ dinv,
                                                  const float* __restrict__ h1,
                                                  float* __restrict__ agg) {
    int e = blockIdx.x * 4 + (threadIdx.x >> 6);
    if (e >= NE) return;
    int l = threadIdx.x & 63;
    int s = src[e], d = dst[e];
    float w = dinv[s] * dinv[d];
    atomicAdd(&agg[(long)d * HID + l], h1[(long)s * HID + l] * w);
}

// ---- fuse: h = relu(agg + h1*dinv^2 + b1) * mask  (written into agg) ----
__global__ __launch_bounds__(256) void k_fuse1(const float* __restrict__ h1,
                                               float* __restrict__ agg,
                                               const float* __restrict__ dinv,
                                               const float* __restrict__ b1,
                                               const float* __restrict__ mask) {
    int i = blockIdx.x * 256 + threadIdx.x;
    if (i >= NN * HID) return;
    int node = i >> 6, c = i & 63;
    float di = dinv[node];
    float v = agg[i] + h1[i] * di * di + b1[c];
    v = v > 0.f ? v : 0.f;
    agg[i] = v * mask[i];
}

// ---- h2 = h @ W2 : [NN,64] @ [64,40]  (32 rows per 320-thread block) ----
__global__ __launch_bounds__(320) void k_gemm2(const float* __restrict__ h,
                                               const float* __restrict__ W2,
                                               float* __restrict__ h2) {
    __shared__ float sW[HID * OUTD];   // 10 KB
    __shared__ float sH[32 * HID];     // 8 KB
    int t = threadIdx.x;
    for (int i = t; i < HID * OUTD; i += 320) sW[i] = W2[i];
    long row0 = (long)blockIdx.x * 32;
    for (int i = t; i < 32 * HID; i += 320) {
        long r = row0 + (i >> 6);
        sH[i] = (r < NN) ? h[r * HID + (i & 63)] : 0.f;
    }
    __syncthreads();
    int c  = t % OUTD;
    int rg = t / OUTD;                 // 0..7
    float s0 = 0.f, s1 = 0.f, s2 = 0.f, s3 = 0.f;
    #pragma unroll 8
    for (int k = 0; k < HID; ++k) {
        float w = sW[k * OUTD + c];
        s0 = fmaf(sH[(rg * 4 + 0) * HID + k], w, s0);
        s1 = fmaf(sH[(rg * 4 + 1) * HID + k], w, s1);
        s2 = fmaf(sH[(rg * 4 + 2) * HID + k], w, s2);
        s3 = fmaf(sH[(rg * 4 + 3) * HID + k], w, s3);
    }
    float sv[4] = {s0, s1, s2, s3};
    #pragma unroll
    for (int j = 0; j < 4; ++j) {
        long row = row0 + rg * 4 + j;
        if (row < NN) h2[row * OUTD + c] = sv[j];
    }
}

// ---- scatter conv2: out[dst] += h2[src] * norm  (flattened E*40 index space) ----
__global__ __launch_bounds__(256) void k_scatter2(const int* __restrict__ src,
                                                  const int* __restrict__ dst,
                                                  const float* __restrict__ dinv,
                                                  const float* __restrict__ h2,
                                                  float* __restrict__ out) {
    int idx = blockIdx.x * 256 + threadIdx.x;
    if (idx >= NE * OUTD) return;      // 64M < 2^31
    int e = idx / OUTD;
    int c = idx - e * OUTD;
    int s = src[e], d = dst[e];
    float w = dinv[s] * dinv[d];
    atomicAdd(&out[(long)d * OUTD + c], h2[(long)s * OUTD + c] * w);
}

// ---- epilogue conv2: out += h2*dinv^2 + b2 ----
__global__ __launch_bounds__(256) void k_final(const float* __restrict__ h2,
                                               const float* __restrict__ dinv,
                                               const float* __restrict__ b2,
                                               float* __restrict__ out) {
    int i = blockIdx.x * 256 + threadIdx.x;
    if (i >= NN * OUTD) return;
    int node = i / OUTD, c = i - node * OUTD;
    float di = dinv[node];
    out[i] += h2[i] * di * di + b2[c];
}

extern "C" void kernel_launch(void* const* d_in, const int* in_sizes, int n_in,
                              void* d_out, int out_size, void* d_ws, size_t ws_size,
                              hipStream_t stream) {
    const float* x    = (const float*)d_in[0];
    const int*   ei   = (const int*)d_in[1];
    const int*   src  = ei;
    const int*   dst  = ei + NE;
    const float* W1   = (const float*)d_in[2];
    const float* b1   = (const float*)d_in[3];
    const float* W2   = (const float*)d_in[4];
    const float* b2   = (const float*)d_in[5];
    const float* mask = (const float*)d_in[6];
    float* out = (float*)d_out;

    float* ws   = (float*)d_ws;
    float* deg  = ws;                                   // NN   (becomes dinv)
    float* h1   = ws + NN;                              // NN*64 (reused as h2: NN*40)
    float* agg1 = ws + NN + (long)NN * HID;             // NN*64

    hipMemsetAsync(deg, 0, NN * sizeof(float), stream);
    hipMemsetAsync(agg1, 0, (size_t)NN * HID * sizeof(float), stream);
    hipMemsetAsync(d_out, 0, (size_t)NN * OUTD * sizeof(float), stream);

    k_deg<<<(NE + 255) / 256, 256, 0, stream>>>(dst, deg);
    k_dinv<<<(NN + 255) / 256, 256, 0, stream>>>(deg);
    k_gemm1<<<(NN + 15) / 16, 256, 0, stream>>>(x, W1, h1);
    k_scatter1<<<(NE + 3) / 4, 256, 0, stream>>>(src, dst, deg, h1, agg1);
    k_fuse1<<<(NN * HID + 255) / 256, 256, 0, stream>>>(h1, agg1, deg, b1, mask);

    float* h2 = h1;  // reuse
    k_gemm2<<<(NN + 31) / 32, 320, 0, stream>>>(agg1, W2, h2);
    k_scatter2<<<(NE * OUTD + 255) / 256, 256, 0, stream>>>(src, dst, deg, h2, out);
    k_final<<<(NN * OUTD + 255) / 256, 256, 0, stream>>>(h2, deg, b2, out);
}

// Round 2
// 494.187 us; speedup vs baseline: 1.6421x; 1.6421x over previous
//
#include <hip/hip_runtime.h>

#define NN   100000
#define NE   1600000
#define FEAT 128
#define HID  64
#define OUTD 40
#define NB   ((NN + 255) / 256)   // 391 blocks for node-sized scans

// ---- 1. integer in-degree count ----
__global__ __launch_bounds__(256) void k_deg(const int* __restrict__ dst,
                                             int* __restrict__ ideg) {
    int e = blockIdx.x * 256 + threadIdx.x;
    if (e < NE) atomicAdd(&ideg[dst[e]], 1);
}

// ---- 2. dinv[i] = rsqrt(deg+1) ----
__global__ __launch_bounds__(256) void k_dinv(const int* __restrict__ ideg,
                                              float* __restrict__ dinv) {
    int i = blockIdx.x * 256 + threadIdx.x;
    if (i < NN) dinv[i] = rsqrtf((float)ideg[i] + 1.0f);
}

// ---- 3a. per-block degree sums ----
__global__ __launch_bounds__(256) void k_bsum(const int* __restrict__ ideg,
                                              int* __restrict__ bsum) {
    __shared__ int s[256];
    int i = blockIdx.x * 256 + threadIdx.x;
    s[threadIdx.x] = (i < NN) ? ideg[i] : 0;
    __syncthreads();
    for (int st = 128; st > 0; st >>= 1) {
        if (threadIdx.x < st) s[threadIdx.x] += s[threadIdx.x + st];
        __syncthreads();
    }
    if (threadIdx.x == 0) bsum[blockIdx.x] = s[0];
}

// ---- 3b. exclusive scan of block sums (single block, 512 >= NB) ----
__global__ __launch_bounds__(512) void k_scanb(int* __restrict__ bsum) {
    __shared__ int s[512];
    int t = threadIdx.x;
    int mine = (t < NB) ? bsum[t] : 0;
    s[t] = mine;
    __syncthreads();
    for (int off = 1; off < 512; off <<= 1) {
        int v = (t >= off) ? s[t - off] : 0;
        __syncthreads();
        s[t] += v;
        __syncthreads();
    }
    if (t < NB) bsum[t] = s[t] - mine;   // exclusive
}

// ---- 3c. per-element exclusive scan -> row_ptr ----
__global__ __launch_bounds__(256) void k_scan3(const int* __restrict__ ideg,
                                               const int* __restrict__ bsum,
                                               int* __restrict__ row_ptr) {
    __shared__ int s[256];
    int t = threadIdx.x;
    int i = blockIdx.x * 256 + t;
    int mine = (i < NN) ? ideg[i] : 0;
    s[t] = mine;
    __syncthreads();
    for (int off = 1; off < 256; off <<= 1) {
        int v = (t >= off) ? s[t - off] : 0;
        __syncthreads();
        s[t] += v;
        __syncthreads();
    }
    if (i < NN) row_ptr[i] = bsum[blockIdx.x] + s[t] - mine;
    if (i == NN - 1) row_ptr[NN] = bsum[blockIdx.x] + s[t];
}

// ---- 4. place edges into CSR buckets ----
__global__ __launch_bounds__(256) void k_place(const int* __restrict__ src,
                                               const int* __restrict__ dst,
                                               const int* __restrict__ row_ptr,
                                               int* __restrict__ cnt,
                                               int* __restrict__ csr_src) {
    int e = blockIdx.x * 256 + threadIdx.x;
    if (e >= NE) return;
    int d = dst[e];
    int pos = row_ptr[d] + atomicAdd(&cnt[d], 1);
    csr_src[pos] = src[e];
}

// ---- 5. h1 = x @ W1 : [NN,128] @ [128,64] ----
__global__ __launch_bounds__(256) void k_gemm1(const float* __restrict__ x,
                                               const float* __restrict__ W1,
                                               float* __restrict__ h1) {
    __shared__ float sW[FEAT * HID];   // 32 KB
    __shared__ float sX[16 * FEAT];    // 8 KB
    int t = threadIdx.x;
    for (int i = t; i < FEAT * HID; i += 256) sW[i] = W1[i];
    int row0 = blockIdx.x * 16;
    for (int i = t; i < 16 * FEAT; i += 256) {
        int r = row0 + (i >> 7);
        sX[i] = (r < NN) ? x[(long)r * FEAT + (i & 127)] : 0.f;
    }
    __syncthreads();
    int c  = t & 63;
    int rg = t >> 6;
    float s0 = 0.f, s1 = 0.f, s2 = 0.f, s3 = 0.f;
    #pragma unroll 8
    for (int k = 0; k < FEAT; ++k) {
        float w = sW[k * HID + c];
        s0 = fmaf(sX[(rg * 4 + 0) * FEAT + k], w, s0);
        s1 = fmaf(sX[(rg * 4 + 1) * FEAT + k], w, s1);
        s2 = fmaf(sX[(rg * 4 + 2) * FEAT + k], w, s2);
        s3 = fmaf(sX[(rg * 4 + 3) * FEAT + k], w, s3);
    }
    float sv[4] = {s0, s1, s2, s3};
    #pragma unroll
    for (int j = 0; j < 4; ++j) {
        int row = row0 + rg * 4 + j;
        if (row < NN) h1[(long)row * HID + c] = sv[j];
    }
}

// ---- 6. conv1 aggregate (gather) + self-loop + bias + relu + dropout ----
// one wave per node; lane = feature column
__global__ __launch_bounds__(256) void k_agg1(const int* __restrict__ row_ptr,
                                              const int* __restrict__ csr_src,
                                              const float* __restrict__ dinv,
                                              const float* __restrict__ h1,
                                              const float* __restrict__ b1,
                                              const float* __restrict__ mask,
                                              float* __restrict__ h) {
    int node = blockIdx.x * 4 + (threadIdx.x >> 6);
    if (node >= NN) return;
    int l = threadIdx.x & 63;
    int beg = row_ptr[node], end = row_ptr[node + 1];
    float di = dinv[node];
    float acc = 0.f;
    for (int j0 = beg; j0 < end; j0 += 64) {
        int n = end - j0;
        int m = n < 64 ? n : 64;
        int   sl = 0;
        float wl = 0.f;
        if (l < m) { sl = csr_src[j0 + l]; wl = dinv[sl] * di; }
        for (int j = 0; j < m; ++j) {
            int   s = __shfl(sl, j);
            float w = __shfl(wl, j);
            acc = fmaf(h1[s * HID + l], w, acc);
        }
    }
    float selfv = h1[node * HID + l];
    float v = acc + selfv * di * di + b1[l];
    v = v > 0.f ? v : 0.f;
    h[node * HID + l] = v * mask[node * HID + l];
}

// ---- 7. h2 = h @ W2 : [NN,64] @ [64,40] ----
__global__ __launch_bounds__(320) void k_gemm2(const float* __restrict__ h,
                                               const float* __restrict__ W2,
                                               float* __restrict__ h2) {
    __shared__ float sW[HID * OUTD];
    __shared__ float sH[32 * HID];
    int t = threadIdx.x;
    for (int i = t; i < HID * OUTD; i += 320) sW[i] = W2[i];
    int row0 = blockIdx.x * 32;
    for (int i = t; i < 32 * HID; i += 320) {
        int r = row0 + (i >> 6);
        sH[i] = (r < NN) ? h[(long)r * HID + (i & 63)] : 0.f;
    }
    __syncthreads();
    int c  = t % OUTD;
    int rg = t / OUTD;
    float s0 = 0.f, s1 = 0.f, s2 = 0.f, s3 = 0.f;
    #pragma unroll 8
    for (int k = 0; k < HID; ++k) {
        float w = sW[k * OUTD + c];
        s0 = fmaf(sH[(rg * 4 + 0) * HID + k], w, s0);
        s1 = fmaf(sH[(rg * 4 + 1) * HID + k], w, s1);
        s2 = fmaf(sH[(rg * 4 + 2) * HID + k], w, s2);
        s3 = fmaf(sH[(rg * 4 + 3) * HID + k], w, s3);
    }
    float sv[4] = {s0, s1, s2, s3};
    #pragma unroll
    for (int j = 0; j < 4; ++j) {
        int row = row0 + rg * 4 + j;
        if (row < NN) h2[(long)row * OUTD + c] = sv[j];
    }
}

// ---- 8. conv2 aggregate (gather) + self-loop + bias -> out ----
__global__ __launch_bounds__(256) void k_agg2(const int* __restrict__ row_ptr,
                                              const int* __restrict__ csr_src,
                                              const float* __restrict__ dinv,
                                              const float* __restrict__ h2,
                                              const float* __restrict__ b2,
                                              float* __restrict__ out) {
    int node = blockIdx.x * 4 + (threadIdx.x >> 6);
    if (node >= NN) return;
    int l = threadIdx.x & 63;
    int c = l < OUTD ? l : OUTD - 1;   // clamp inactive lanes
    int beg = row_ptr[node], end = row_ptr[node + 1];
    float di = dinv[node];
    float acc = 0.f;
    for (int j0 = beg; j0 < end; j0 += 64) {
        int n = end - j0;
        int m = n < 64 ? n : 64;
        int   sl = 0;
        float wl = 0.f;
        if (l < m) { sl = csr_src[j0 + l]; wl = dinv[sl] * di; }
        for (int j = 0; j < m; ++j) {
            int   s = __shfl(sl, j);
            float w = __shfl(wl, j);
            acc = fmaf(h2[s * OUTD + c], w, acc);
        }
    }
    if (l < OUTD) {
        float selfv = h2[node * OUTD + c];
        out[node * OUTD + c] = acc + selfv * di * di + b2[c];
    }
}

extern "C" void kernel_launch(void* const* d_in, const int* in_sizes, int n_in,
                              void* d_out, int out_size, void* d_ws, size_t ws_size,
                              hipStream_t stream) {
    const float* x    = (const float*)d_in[0];
    const int*   ei   = (const int*)d_in[1];
    const int*   src  = ei;
    const int*   dst  = ei + NE;
    const float* W1   = (const float*)d_in[2];
    const float* b1   = (const float*)d_in[3];
    const float* W2   = (const float*)d_in[4];
    const float* b2   = (const float*)d_in[5];
    const float* mask = (const float*)d_in[6];
    float* out = (float*)d_out;

    char* ws = (char*)d_ws;
    int*   ideg    = (int*)ws;                 ws += (size_t)NN * 4;
    int*   row_ptr = (int*)ws;                 ws += (size_t)(NN + 1) * 4;
    int*   cnt     = (int*)ws;                 ws += (size_t)NN * 4;
    int*   bsum    = (int*)ws;                 ws += 512 * 4;
    float* dinv    = (float*)ws;               ws += (size_t)NN * 4;
    int*   csr_src = (int*)ws;                 ws += (size_t)NE * 4;
    float* h1      = (float*)ws;               ws += (size_t)NN * HID * 4;  // reused as h2
    float* h       = (float*)ws;               ws += (size_t)NN * HID * 4;

    hipMemsetAsync(ideg, 0, (size_t)NN * 4, stream);
    hipMemsetAsync(cnt,  0, (size_t)NN * 4, stream);

    k_deg  <<<(NE + 255) / 256, 256, 0, stream>>>(dst, ideg);
    k_dinv <<<NB, 256, 0, stream>>>(ideg, dinv);
    k_bsum <<<NB, 256, 0, stream>>>(ideg, bsum);
    k_scanb<<<1, 512, 0, stream>>>(bsum);
    k_scan3<<<NB, 256, 0, stream>>>(ideg, bsum, row_ptr);
    k_place<<<(NE + 255) / 256, 256, 0, stream>>>(src, dst, row_ptr, cnt, csr_src);

    k_gemm1<<<(NN + 15) / 16, 256, 0, stream>>>(x, W1, h1);
    k_agg1 <<<(NN + 3) / 4, 256, 0, stream>>>(row_ptr, csr_src, dinv, h1, b1, mask, h);

    float* h2 = h1;  // h1 dead after k_agg1
    k_gemm2<<<(NN + 31) / 32, 320, 0, stream>>>(h, W2, h2);
    k_agg2 <<<(NN + 3) / 4, 256, 0, stream>>>(row_ptr, csr_src, dinv, h2, b2, out);
}

// Round 3
// 319.713 us; speedup vs baseline: 2.5382x; 1.5457x over previous
//
#include <hip/hip_runtime.h>

#define NN   100000
#define NE   1600000
#define FEAT 128
#define HID  64
#define OUTD 40
#define BSH  8                       // bucket = dst >> 8  (256 nodes/bucket)
#define NBKT ((NN + 255) / 256)      // 391
#define CCHUNK 6144                  // edges per block in pair-scatter

// ---- A. bucket histogram (LDS per block, merged once) ----
__global__ __launch_bounds__(256) void k_hist(const int* __restrict__ dst,
                                              int* __restrict__ btot) {
    __shared__ int h[NBKT];
    for (int i = threadIdx.x; i < NBKT; i += 256) h[i] = 0;
    __syncthreads();
    int stride = gridDim.x * 256;
    for (int e = blockIdx.x * 256 + threadIdx.x; e < NE; e += stride)
        atomicAdd(&h[dst[e] >> BSH], 1);
    __syncthreads();
    for (int i = threadIdx.x; i < NBKT; i += 256)
        if (h[i]) atomicAdd(&btot[i], h[i]);
}

// ---- B. exclusive scan of bucket totals (single block; 512 >= NBKT) ----
__global__ __launch_bounds__(512) void k_bscan(const int* __restrict__ btot,
                                               int* __restrict__ bbase) {
    __shared__ int s[512];
    int t = threadIdx.x;
    int v = (t < NBKT) ? btot[t] : 0;
    s[t] = v;
    __syncthreads();
    for (int off = 1; off < 512; off <<= 1) {
        int u = (t >= off) ? s[t - off] : 0;
        __syncthreads();
        s[t] += u;
        __syncthreads();
    }
    if (t < NBKT) bbase[t] = s[t] - v;
}

// ---- C. scatter (src,dst) pairs into bucket segments (block-exclusive runs) ----
__global__ __launch_bounds__(256) void k_pairs(const int* __restrict__ src,
                                               const int* __restrict__ dst,
                                               const int* __restrict__ bbase,
                                               int* __restrict__ bfill,
                                               int2* __restrict__ pairs) {
    __shared__ int bcnt[NBKT];
    __shared__ int gb[NBKT];
    for (int i = threadIdx.x; i < NBKT; i += 256) bcnt[i] = 0;
    __syncthreads();
    int e0 = blockIdx.x * CCHUNK;
    int e1 = min(NE, e0 + CCHUNK);
    for (int e = e0 + threadIdx.x; e < e1; e += 256)
        atomicAdd(&bcnt[dst[e] >> BSH], 1);
    __syncthreads();
    for (int i = threadIdx.x; i < NBKT; i += 256) {
        int c = bcnt[i];
        gb[i] = c ? (bbase[i] + atomicAdd(&bfill[i], c)) : 0;
        bcnt[i] = 0;
    }
    __syncthreads();
    for (int e = e0 + threadIdx.x; e < e1; e += 256) {
        int d = dst[e];
        int b = d >> BSH;
        int idx = gb[b] + atomicAdd(&bcnt[b], 1);
        pairs[idx] = make_int2(src[e], d);
    }
}

// ---- D. per-bucket CSR build: row_ptr, dinv, csr_src (all LDS-local) ----
__global__ __launch_bounds__(256) void k_csr(const int2* __restrict__ pairs,
                                             const int* __restrict__ btot,
                                             const int* __restrict__ bbase,
                                             int* __restrict__ row_ptr,
                                             float* __restrict__ dinv,
                                             int* __restrict__ csr_src) {
    __shared__ int nd[256];
    __shared__ int sc[256];
    __shared__ int ro[257];
    __shared__ int cnt2[256];
    int b = blockIdx.x;
    int t = threadIdx.x;
    int node0 = b << BSH;
    int nNodes = min(256, NN - node0);
    int base = bbase[b];
    int count = btot[b];
    nd[t] = 0; cnt2[t] = 0;
    __syncthreads();
    for (int i = t; i < count; i += 256)
        atomicAdd(&nd[pairs[base + i].y & 255], 1);
    __syncthreads();
    int v = nd[t];
    sc[t] = v;
    __syncthreads();
    for (int off = 1; off < 256; off <<= 1) {
        int u = (t >= off) ? sc[t - off] : 0;
        __syncthreads();
        sc[t] += u;
        __syncthreads();
    }
    ro[t + 1] = sc[t];
    if (t == 0) ro[0] = 0;
    __syncthreads();
    if (t < nNodes) {
        row_ptr[node0 + t] = base + ro[t];
        dinv[node0 + t] = rsqrtf((float)v + 1.0f);
    }
    if (b == NBKT - 1 && t == 0) row_ptr[NN] = NE;
    for (int i = t; i < count; i += 256) {
        int2 p = pairs[base + i];
        int dl = p.y & 255;
        int pos = ro[dl] + atomicAdd(&cnt2[dl], 1);
        csr_src[base + pos] = p.x;
    }
}

// ---- E. edge weights: csr_w[pos] = dinv[src]*dinv[dst] ----
__global__ __launch_bounds__(256) void k_wts(const int* __restrict__ row_ptr,
                                             const int* __restrict__ csr_src,
                                             const float* __restrict__ dinv,
                                             float* __restrict__ csr_w) {
    int node = blockIdx.x * 4 + (threadIdx.x >> 6);
    if (node >= NN) return;
    int l = threadIdx.x & 63;
    int beg = row_ptr[node], end = row_ptr[node + 1];
    float di = dinv[node];
    for (int j = beg + l; j < end; j += 64)
        csr_w[j] = dinv[csr_src[j]] * di;
}

// ---- h1 = x @ W1 : [NN,128] @ [128,64] ----
__global__ __launch_bounds__(256) void k_gemm1(const float* __restrict__ x,
                                               const float* __restrict__ W1,
                                               float* __restrict__ h1) {
    __shared__ float sW[FEAT * HID];
    __shared__ float sX[16 * FEAT];
    int t = threadIdx.x;
    for (int i = t; i < FEAT * HID; i += 256) sW[i] = W1[i];
    int row0 = blockIdx.x * 16;
    for (int i = t; i < 16 * FEAT; i += 256) {
        int r = row0 + (i >> 7);
        sX[i] = (r < NN) ? x[(long)r * FEAT + (i & 127)] : 0.f;
    }
    __syncthreads();
    int c  = t & 63;
    int rg = t >> 6;
    float s0 = 0.f, s1 = 0.f, s2 = 0.f, s3 = 0.f;
    #pragma unroll 8
    for (int k = 0; k < FEAT; ++k) {
        float w = sW[k * HID + c];
        s0 = fmaf(sX[(rg * 4 + 0) * FEAT + k], w, s0);
        s1 = fmaf(sX[(rg * 4 + 1) * FEAT + k], w, s1);
        s2 = fmaf(sX[(rg * 4 + 2) * FEAT + k], w, s2);
        s3 = fmaf(sX[(rg * 4 + 3) * FEAT + k], w, s3);
    }
    float sv[4] = {s0, s1, s2, s3};
    #pragma unroll
    for (int j = 0; j < 4; ++j) {
        int row = row0 + rg * 4 + j;
        if (row < NN) h1[(long)row * HID + c] = sv[j];
    }
}

// ---- conv1 aggregate (scalar-indexed gather, unroll 4) + epilogue ----
__global__ __launch_bounds__(256) void k_agg1(const int* __restrict__ row_ptr,
                                              const int* __restrict__ csr_src,
                                              const float* __restrict__ csr_w,
                                              const float* __restrict__ dinv,
                                              const float* __restrict__ h1,
                                              const float* __restrict__ b1,
                                              const float* __restrict__ mask,
                                              float* __restrict__ h) {
    int node = blockIdx.x * 4 + (threadIdx.x >> 6);
    if (node >= NN) return;
    int l = threadIdx.x & 63;
    int beg = __builtin_amdgcn_readfirstlane(row_ptr[node]);
    int end = __builtin_amdgcn_readfirstlane(row_ptr[node + 1]);
    float acc = 0.f;
    int j = beg;
    for (; j + 4 <= end; j += 4) {
        int   s0 = csr_src[j],   s1 = csr_src[j+1], s2 = csr_src[j+2], s3 = csr_src[j+3];
        float w0 = csr_w[j],     w1 = csr_w[j+1],   w2 = csr_w[j+2],   w3 = csr_w[j+3];
        float a0 = h1[s0 * HID + l];
        float a1 = h1[s1 * HID + l];
        float a2 = h1[s2 * HID + l];
        float a3 = h1[s3 * HID + l];
        acc = fmaf(a0, w0, acc);
        acc = fmaf(a1, w1, acc);
        acc = fmaf(a2, w2, acc);
        acc = fmaf(a3, w3, acc);
    }
    for (; j < end; ++j)
        acc = fmaf(h1[csr_src[j] * HID + l], csr_w[j], acc);
    float di = dinv[node];
    float vv = acc + h1[node * HID + l] * di * di + b1[l];
    vv = vv > 0.f ? vv : 0.f;
    h[node * HID + l] = vv * mask[node * HID + l];
}

// ---- h2 = h @ W2 : [NN,64] @ [64,40] ----
__global__ __launch_bounds__(320) void k_gemm2(const float* __restrict__ h,
                                               const float* __restrict__ W2,
                                               float* __restrict__ h2) {
    __shared__ float sW[HID * OUTD];
    __shared__ float sH[32 * HID];
    int t = threadIdx.x;
    for (int i = t; i < HID * OUTD; i += 320) sW[i] = W2[i];
    int row0 = blockIdx.x * 32;
    for (int i = t; i < 32 * HID; i += 320) {
        int r = row0 + (i >> 6);
        sH[i] = (r < NN) ? h[(long)r * HID + (i & 63)] : 0.f;
    }
    __syncthreads();
    int c  = t % OUTD;
    int rg = t / OUTD;
    float s0 = 0.f, s1 = 0.f, s2 = 0.f, s3 = 0.f;
    #pragma unroll 8
    for (int k = 0; k < HID; ++k) {
        float w = sW[k * OUTD + c];
        s0 = fmaf(sH[(rg * 4 + 0) * HID + k], w, s0);
        s1 = fmaf(sH[(rg * 4 + 1) * HID + k], w, s1);
        s2 = fmaf(sH[(rg * 4 + 2) * HID + k], w, s2);
        s3 = fmaf(sH[(rg * 4 + 3) * HID + k], w, s3);
    }
    float sv[4] = {s0, s1, s2, s3};
    #pragma unroll
    for (int j = 0; j < 4; ++j) {
        int row = row0 + rg * 4 + j;
        if (row < NN) h2[(long)row * OUTD + c] = sv[j];
    }
}

// ---- conv2 aggregate (scalar-indexed gather, unroll 4) + epilogue -> out ----
__global__ __launch_bounds__(256) void k_agg2(const int* __restrict__ row_ptr,
                                              const int* __restrict__ csr_src,
                                              const float* __restrict__ csr_w,
                                              const float* __restrict__ dinv,
                                              const float* __restrict__ h2,
                                              const float* __restrict__ b2,
                                              float* __restrict__ out) {
    int node = blockIdx.x * 4 + (threadIdx.x >> 6);
    if (node >= NN) return;
    int l = threadIdx.x & 63;
    int c = l < OUTD ? l : OUTD - 1;
    int beg = __builtin_amdgcn_readfirstlane(row_ptr[node]);
    int end = __builtin_amdgcn_readfirstlane(row_ptr[node + 1]);
    float acc = 0.f;
    int j = beg;
    for (; j + 4 <= end; j += 4) {
        int   s0 = csr_src[j],   s1 = csr_src[j+1], s2 = csr_src[j+2], s3 = csr_src[j+3];
        float w0 = csr_w[j],     w1 = csr_w[j+1],   w2 = csr_w[j+2],   w3 = csr_w[j+3];
        float a0 = h2[s0 * OUTD + c];
        float a1 = h2[s1 * OUTD + c];
        float a2 = h2[s2 * OUTD + c];
        float a3 = h2[s3 * OUTD + c];
        acc = fmaf(a0, w0, acc);
        acc = fmaf(a1, w1, acc);
        acc = fmaf(a2, w2, acc);
        acc = fmaf(a3, w3, acc);
    }
    for (; j < end; ++j)
        acc = fmaf(h2[csr_src[j] * OUTD + c], csr_w[j], acc);
    if (l < OUTD) {
        float di = dinv[node];
        out[node * OUTD + c] = acc + h2[node * OUTD + c] * di * di + b2[c];
    }
}

extern "C" void kernel_launch(void* const* d_in, const int* in_sizes, int n_in,
                              void* d_out, int out_size, void* d_ws, size_t ws_size,
                              hipStream_t stream) {
    const float* x    = (const float*)d_in[0];
    const int*   ei   = (const int*)d_in[1];
    const int*   src  = ei;
    const int*   dst  = ei + NE;
    const float* W1   = (const float*)d_in[2];
    const float* b1   = (const float*)d_in[3];
    const float* W2   = (const float*)d_in[4];
    const float* b2   = (const float*)d_in[5];
    const float* mask = (const float*)d_in[6];
    float* out = (float*)d_out;

    char* ws = (char*)d_ws;
    int*   btot    = (int*)ws;                 ws += (size_t)NBKT * 4;
    int*   bfill   = (int*)ws;                 ws += (size_t)NBKT * 4;
    int*   bbase   = (int*)ws;                 ws += (size_t)NBKT * 4;
    int*   row_ptr = (int*)ws;                 ws += (size_t)(NN + 1) * 4;
    float* dinv    = (float*)ws;               ws += (size_t)NN * 4;
    int*   csr_src = (int*)ws;                 ws += (size_t)NE * 4;
    float* csr_w   = (float*)ws;               ws += (size_t)NE * 4;
    float* h1      = (float*)ws;               ws += (size_t)NN * HID * 4;  // reused as h2
    float* h       = (float*)ws;               ws += (size_t)NN * HID * 4;
    int2*  pairs   = (int2*)h;                 // alias: pairs dead before h written

    hipMemsetAsync(btot, 0, (size_t)NBKT * 2 * 4, stream);  // btot + bfill

    k_hist <<<512, 256, 0, stream>>>(dst, btot);
    k_bscan<<<1, 512, 0, stream>>>(btot, bbase);
    k_pairs<<<(NE + CCHUNK - 1) / CCHUNK, 256, 0, stream>>>(src, dst, bbase, bfill, pairs);
    k_csr  <<<NBKT, 256, 0, stream>>>(pairs, btot, bbase, row_ptr, dinv, csr_src);
    k_wts  <<<(NN + 3) / 4, 256, 0, stream>>>(row_ptr, csr_src, dinv, csr_w);

    k_gemm1<<<(NN + 15) / 16, 256, 0, stream>>>(x, W1, h1);
    k_agg1 <<<(NN + 3) / 4, 256, 0, stream>>>(row_ptr, csr_src, csr_w, dinv, h1, b1, mask, h);

    float* h2 = h1;  // h1 dead after k_agg1
    k_gemm2<<<(NN + 31) / 32, 320, 0, stream>>>(h, W2, h2);
    k_agg2 <<<(NN + 3) / 4, 256, 0, stream>>>(row_ptr, csr_src, csr_w, dinv, h2, b2, out);
}

// Round 4
// 314.581 us; speedup vs baseline: 2.5796x; 1.0163x over previous
//
#include <hip/hip_runtime.h>
#include <hip/hip_fp16.h>

#define NN   100000
#define NE   1600000
#define FEAT 128
#define HID  64
#define OUTD 40
#define BSH  8                       // bucket = dst >> 8 (256 nodes/bucket)
#define NBKT ((NN + 255) / 256)      // 391
#define CAP  5120                    // padded bucket capacity (mean 4096, sd 64)
#define CCHUNK 6144                  // edges per block in pair-scatter

// ---- A. scatter packed (src<<8|dl) into padded bucket segments ----
__global__ __launch_bounds__(256) void k_pairs(const int* __restrict__ src,
                                               const int* __restrict__ dst,
                                               int* __restrict__ bfill,
                                               int* __restrict__ pairs) {
    __shared__ int bcnt[NBKT];
    __shared__ int gb[NBKT];
    for (int i = threadIdx.x; i < NBKT; i += 256) bcnt[i] = 0;
    __syncthreads();
    int e0 = blockIdx.x * CCHUNK;
    int e1 = min(NE, e0 + CCHUNK);
    for (int e = e0 + threadIdx.x; e < e1; e += 256)
        atomicAdd(&bcnt[dst[e] >> BSH], 1);
    __syncthreads();
    for (int i = threadIdx.x; i < NBKT; i += 256) {
        int c = bcnt[i];
        gb[i] = c ? (i * CAP + atomicAdd(&bfill[i], c)) : 0;
        bcnt[i] = 0;
    }
    __syncthreads();
    for (int e = e0 + threadIdx.x; e < e1; e += 256) {
        int d = dst[e];
        int b = d >> BSH;
        int idx = gb[b] + atomicAdd(&bcnt[b], 1);
        pairs[idx] = (src[e] << 8) | (d & 255);
    }
}

// ---- B. per-bucket CSR: row_beg/row_end, dinv, csr_src (LDS-local) ----
__global__ __launch_bounds__(256) void k_csr(const int* __restrict__ pairs,
                                             const int* __restrict__ bfill,
                                             int* __restrict__ row_beg,
                                             int* __restrict__ row_end,
                                             float* __restrict__ dinv,
                                             int* __restrict__ csr_src) {
    __shared__ int nd[256];
    __shared__ int sc[256];
    __shared__ int ro[257];
    __shared__ int cnt2[256];
    int b = blockIdx.x;
    int t = threadIdx.x;
    int node0 = b << BSH;
    int base  = b * CAP;
    int count = bfill[b];
    nd[t] = 0; cnt2[t] = 0;
    __syncthreads();
    for (int i = t; i < count; i += 256)
        atomicAdd(&nd[pairs[base + i] & 255], 1);
    __syncthreads();
    int v = nd[t];
    sc[t] = v;
    __syncthreads();
    for (int off = 1; off < 256; off <<= 1) {
        int u = (t >= off) ? sc[t - off] : 0;
        __syncthreads();
        sc[t] += u;
        __syncthreads();
    }
    ro[t + 1] = sc[t];
    if (t == 0) ro[0] = 0;
    __syncthreads();
    int node = node0 + t;
    if (node < NN) {
        row_beg[node] = base + ro[t];
        row_end[node] = base + sc[t];
        dinv[node]    = rsqrtf((float)v + 1.0f);
    }
    for (int i = t; i < count; i += 256) {
        int p  = pairs[base + i];
        int dl = p & 255;
        int pos = ro[dl] + atomicAdd(&cnt2[dl], 1);
        csr_src[base + pos] = p >> 8;
    }
}

// ---- h1 = x @ W1 : [NN,128] @ [128,64]  (fp32 + fp16 copies) ----
__global__ __launch_bounds__(256) void k_gemm1(const float* __restrict__ x,
                                               const float* __restrict__ W1,
                                               float* __restrict__ h1,
                                               __half* __restrict__ h1h) {
    __shared__ float sW[FEAT * HID];
    __shared__ float sX[16 * FEAT];
    int t = threadIdx.x;
    for (int i = t; i < FEAT * HID; i += 256) sW[i] = W1[i];
    int row0 = blockIdx.x * 16;
    for (int i = t; i < 16 * FEAT; i += 256) {
        int r = row0 + (i >> 7);
        sX[i] = (r < NN) ? x[(long)r * FEAT + (i & 127)] : 0.f;
    }
    __syncthreads();
    int c  = t & 63;
    int rg = t >> 6;
    float s0 = 0.f, s1 = 0.f, s2 = 0.f, s3 = 0.f;
    #pragma unroll 8
    for (int k = 0; k < FEAT; ++k) {
        float w = sW[k * HID + c];
        s0 = fmaf(sX[(rg * 4 + 0) * FEAT + k], w, s0);
        s1 = fmaf(sX[(rg * 4 + 1) * FEAT + k], w, s1);
        s2 = fmaf(sX[(rg * 4 + 2) * FEAT + k], w, s2);
        s3 = fmaf(sX[(rg * 4 + 3) * FEAT + k], w, s3);
    }
    float sv[4] = {s0, s1, s2, s3};
    #pragma unroll
    for (int j = 0; j < 4; ++j) {
        int row = row0 + rg * 4 + j;
        if (row < NN) {
            h1 [(long)row * HID + c] = sv[j];
            h1h[(long)row * HID + c] = __float2half(sv[j]);
        }
    }
}

// ---- conv1 aggregate: fp16 gathers, unroll-8, on-the-fly weights ----
__global__ __launch_bounds__(256) void k_agg1(const int* __restrict__ row_beg,
                                              const int* __restrict__ row_end,
                                              const int* __restrict__ csr_src,
                                              const float* __restrict__ dinv,
                                              const __half* __restrict__ h1h,
                                              const float* __restrict__ h1,
                                              const float* __restrict__ b1,
                                              const float* __restrict__ mask,
                                              float* __restrict__ h) {
    int node = blockIdx.x * 4 + (threadIdx.x >> 6);
    if (node >= NN) return;
    int l = threadIdx.x & 63;
    int beg = __builtin_amdgcn_readfirstlane(row_beg[node]);
    int end = __builtin_amdgcn_readfirstlane(row_end[node]);
    float di = dinv[node];
    float acc = 0.f;
    for (int j0 = beg; j0 < end; j0 += 8) {
        #pragma unroll
        for (int k = 0; k < 8; ++k) {
            int jj = j0 + k;
            bool valid = jj < end;
            int idx = valid ? jj : beg;
            int s = csr_src[idx];
            float w = valid ? dinv[s] * di : 0.f;
            float a = __half2float(h1h[s * HID + l]);
            acc = fmaf(a, w, acc);
        }
    }
    float vv = acc + h1[node * HID + l] * di * di + b1[l];
    vv = vv > 0.f ? vv : 0.f;
    h[node * HID + l] = vv * mask[node * HID + l];
}

// ---- h2 = h @ W2 : [NN,64] @ [64,40]  (fp32 + fp16 copies) ----
__global__ __launch_bounds__(320) void k_gemm2(const float* __restrict__ h,
                                               const float* __restrict__ W2,
                                               float* __restrict__ h2,
                                               __half* __restrict__ h2h) {
    __shared__ float sW[HID * OUTD];
    __shared__ float sH[32 * HID];
    int t = threadIdx.x;
    for (int i = t; i < HID * OUTD; i += 320) sW[i] = W2[i];
    int row0 = blockIdx.x * 32;
    for (int i = t; i < 32 * HID; i += 320) {
        int r = row0 + (i >> 6);
        sH[i] = (r < NN) ? h[(long)r * HID + (i & 63)] : 0.f;
    }
    __syncthreads();
    int c  = t % OUTD;
    int rg = t / OUTD;
    float s0 = 0.f, s1 = 0.f, s2 = 0.f, s3 = 0.f;
    #pragma unroll 8
    for (int k = 0; k < HID; ++k) {
        float w = sW[k * OUTD + c];
        s0 = fmaf(sH[(rg * 4 + 0) * HID + k], w, s0);
        s1 = fmaf(sH[(rg * 4 + 1) * HID + k], w, s1);
        s2 = fmaf(sH[(rg * 4 + 2) * HID + k], w, s2);
        s3 = fmaf(sH[(rg * 4 + 3) * HID + k], w, s3);
    }
    float sv[4] = {s0, s1, s2, s3};
    #pragma unroll
    for (int j = 0; j < 4; ++j) {
        int row = row0 + rg * 4 + j;
        if (row < NN) {
            h2 [(long)row * OUTD + c] = sv[j];
            h2h[(long)row * OUTD + c] = __float2half(sv[j]);
        }
    }
}

// ---- conv2 aggregate: fp16 gathers, unroll-8 -> out ----
__global__ __launch_bounds__(256) void k_agg2(const int* __restrict__ row_beg,
                                              const int* __restrict__ row_end,
                                              const int* __restrict__ csr_src,
                                              const float* __restrict__ dinv,
                                              const __half* __restrict__ h2h,
                                              const float* __restrict__ h2,
                                              const float* __restrict__ b2,
                                              float* __restrict__ out) {
    int node = blockIdx.x * 4 + (threadIdx.x >> 6);
    if (node >= NN) return;
    int l = threadIdx.x & 63;
    int c = l < OUTD ? l : OUTD - 1;
    int beg = __builtin_amdgcn_readfirstlane(row_beg[node]);
    int end = __builtin_amdgcn_readfirstlane(row_end[node]);
    float di = dinv[node];
    float acc = 0.f;
    for (int j0 = beg; j0 < end; j0 += 8) {
        #pragma unroll
        for (int k = 0; k < 8; ++k) {
            int jj = j0 + k;
            bool valid = jj < end;
            int idx = valid ? jj : beg;
            int s = csr_src[idx];
            float w = valid ? dinv[s] * di : 0.f;
            float a = __half2float(h2h[s * OUTD + c]);
            acc = fmaf(a, w, acc);
        }
    }
    if (l < OUTD)
        out[node * OUTD + c] = acc + h2[node * OUTD + c] * di * di + b2[c];
}

extern "C" void kernel_launch(void* const* d_in, const int* in_sizes, int n_in,
                              void* d_out, int out_size, void* d_ws, size_t ws_size,
                              hipStream_t stream) {
    const float* x    = (const float*)d_in[0];
    const int*   ei   = (const int*)d_in[1];
    const int*   src  = ei;
    const int*   dst  = ei + NE;
    const float* W1   = (const float*)d_in[2];
    const float* b1   = (const float*)d_in[3];
    const float* W2   = (const float*)d_in[4];
    const float* b2   = (const float*)d_in[5];
    const float* mask = (const float*)d_in[6];
    float* out = (float*)d_out;

    char* ws = (char*)d_ws;
    int*    bfill   = (int*)ws;                ws += (size_t)NBKT * 4;
    int*    row_beg = (int*)ws;                ws += (size_t)NN * 4;
    int*    row_end = (int*)ws;                ws += (size_t)NN * 4;
    float*  dinv    = (float*)ws;              ws += (size_t)NN * 4;
    int*    csr_src = (int*)ws;                ws += (size_t)NBKT * CAP * 4;   // 8 MB
    float*  h1      = (float*)ws;              ws += (size_t)NN * HID * 4;     // 25.6 MB
    __half* h1h     = (__half*)ws;             ws += (size_t)NN * HID * 2;     // 12.8 MB
    float*  h       = (float*)ws;              ws += (size_t)NN * HID * 4;     // 25.6 MB
    int*    pairs   = (int*)h;                           // alias: dead before h written
    float*  h2      = h1;                                // alias: h1 dead after k_agg1
    __half* h2h     = (__half*)(h1 + (size_t)NN * OUTD); // 16+8 MB < 25.6 MB region

    hipMemsetAsync(bfill, 0, (size_t)NBKT * 4, stream);

    k_pairs<<<(NE + CCHUNK - 1) / CCHUNK, 256, 0, stream>>>(src, dst, bfill, pairs);
    k_csr  <<<NBKT, 256, 0, stream>>>(pairs, bfill, row_beg, row_end, dinv, csr_src);

    k_gemm1<<<(NN + 15) / 16, 256, 0, stream>>>(x, W1, h1, h1h);
    k_agg1 <<<(NN + 3) / 4, 256, 0, stream>>>(row_beg, row_end, csr_src, dinv,
                                              h1h, h1, b1, mask, h);
    k_gemm2<<<(NN + 31) / 32, 320, 0, stream>>>(h, W2, h2, h2h);
    k_agg2 <<<(NN + 3) / 4, 256, 0, stream>>>(row_beg, row_end, csr_src, dinv,
                                              h2h, h2, b2, out);
}

// Round 5
// 306.171 us; speedup vs baseline: 2.6504x; 1.0275x over previous
//
#include <hip/hip_runtime.h>
#include <hip/hip_fp16.h>

#define NN   100000
#define NE   1600000
#define FEAT 128
#define HID  64
#define OUTD 40
#define BSH  8                       // bucket = dst >> 8 (256 nodes/bucket)
#define NBKT ((NN + 255) / 256)      // 391
#define CAP  5120                    // padded bucket capacity (mean 4096, sd 64)
#define CCHUNK 6144                  // edges per block in pair-scatter (mult of 4)

// ---- A. scatter packed (src<<8|dl) into padded bucket segments ----
__global__ __launch_bounds__(256) void k_pairs(const int* __restrict__ src,
                                               const int* __restrict__ dst,
                                               int* __restrict__ bfill,
                                               int* __restrict__ pairs) {
    __shared__ int bcnt[NBKT];
    __shared__ int gb[NBKT];
    for (int i = threadIdx.x; i < NBKT; i += 256) bcnt[i] = 0;
    __syncthreads();
    int e0 = blockIdx.x * CCHUNK;
    int e1 = min(NE, e0 + CCHUNK);
    const int4* d4p = (const int4*)dst;
    const int4* s4p = (const int4*)src;
    for (int q = e0 / 4 + threadIdx.x; q < e1 / 4; q += 256) {
        int4 d4 = d4p[q];
        atomicAdd(&bcnt[d4.x >> BSH], 1);
        atomicAdd(&bcnt[d4.y >> BSH], 1);
        atomicAdd(&bcnt[d4.z >> BSH], 1);
        atomicAdd(&bcnt[d4.w >> BSH], 1);
    }
    __syncthreads();
    for (int i = threadIdx.x; i < NBKT; i += 256) {
        int c = bcnt[i];
        gb[i] = c ? (i * CAP + atomicAdd(&bfill[i], c)) : 0;
        bcnt[i] = 0;
    }
    __syncthreads();
    for (int q = e0 / 4 + threadIdx.x; q < e1 / 4; q += 256) {
        int4 d4 = d4p[q];
        int4 s4 = s4p[q];
        int b, idx;
        b = d4.x >> BSH; idx = gb[b] + atomicAdd(&bcnt[b], 1); pairs[idx] = (s4.x << 8) | (d4.x & 255);
        b = d4.y >> BSH; idx = gb[b] + atomicAdd(&bcnt[b], 1); pairs[idx] = (s4.y << 8) | (d4.y & 255);
        b = d4.z >> BSH; idx = gb[b] + atomicAdd(&bcnt[b], 1); pairs[idx] = (s4.z << 8) | (d4.z & 255);
        b = d4.w >> BSH; idx = gb[b] + atomicAdd(&bcnt[b], 1); pairs[idx] = (s4.w << 8) | (d4.w & 255);
    }
}

// ---- B. per-bucket CSR: row_beg/row_end, dinv, csr.x = src (LDS-local) ----
__global__ __launch_bounds__(256) void k_csr(const int* __restrict__ pairs,
                                             const int* __restrict__ bfill,
                                             int* __restrict__ row_beg,
                                             int* __restrict__ row_end,
                                             float* __restrict__ dinv,
                                             int2* __restrict__ csr) {
    __shared__ int nd[256];
    __shared__ int sc[256];
    __shared__ int ro[257];
    __shared__ int cnt2[256];
    int b = blockIdx.x;
    int t = threadIdx.x;
    int node0 = b << BSH;
    int base  = b * CAP;
    int count = bfill[b];
    nd[t] = 0; cnt2[t] = 0;
    __syncthreads();
    for (int i = t; i < count; i += 256)
        atomicAdd(&nd[pairs[base + i] & 255], 1);
    __syncthreads();
    int v = nd[t];
    sc[t] = v;
    __syncthreads();
    for (int off = 1; off < 256; off <<= 1) {
        int u = (t >= off) ? sc[t - off] : 0;
        __syncthreads();
        sc[t] += u;
        __syncthreads();
    }
    ro[t + 1] = sc[t];
    if (t == 0) ro[0] = 0;
    __syncthreads();
    int node = node0 + t;
    if (node < NN) {
        row_beg[node] = base + ro[t];
        row_end[node] = base + sc[t];
        dinv[node]    = rsqrtf((float)v + 1.0f);
    }
    for (int i = t; i < count; i += 256) {
        int p  = pairs[base + i];
        int dl = p & 255;
        int pos = ro[dl] + atomicAdd(&cnt2[dl], 1);
        csr[base + pos].x = p >> 8;
    }
}

// ---- C. csr.y = bits(dinv[src]*dinv[dst]) ----
__global__ __launch_bounds__(256) void k_wts(const int* __restrict__ row_beg,
                                             const int* __restrict__ row_end,
                                             const float* __restrict__ dinv,
                                             int2* __restrict__ csr) {
    int node = blockIdx.x * 4 + (threadIdx.x >> 6);
    if (node >= NN) return;
    int l = threadIdx.x & 63;
    int beg = row_beg[node], end = row_end[node];
    float di = dinv[node];
    for (int j = beg + l; j < end; j += 64)
        csr[j].y = __float_as_int(dinv[csr[j].x] * di);
}

// ---- h1h = fp16(x @ W1) : [NN,128] @ [128,64] ----
__global__ __launch_bounds__(256) void k_gemm1(const float* __restrict__ x,
                                               const float* __restrict__ W1,
                                               __half* __restrict__ h1h) {
    __shared__ float sWt[HID * 144];      // transposed, stride 144 (2-way banks) 36.9 KB
    __shared__ float sX[16 * FEAT];       // 8 KB
    int t = threadIdx.x;
    for (int i = t; i < FEAT * HID; i += 256) {
        int k = i >> 6, c = i & 63;
        sWt[c * 144 + k] = W1[i];
    }
    int row0 = blockIdx.x * 16;
    const float4* x4 = (const float4*)x;
    float4* sX4 = (float4*)sX;
    for (int i = t; i < 16 * FEAT / 4; i += 256) {
        int r = row0 + (i >> 5);
        sX4[i] = (r < NN) ? x4[(long)r * (FEAT / 4) + (i & 31)]
                          : make_float4(0.f, 0.f, 0.f, 0.f);
    }
    __syncthreads();
    int c  = t & 63;
    int rg = t >> 6;
    float s0 = 0.f, s1 = 0.f, s2 = 0.f, s3 = 0.f;
    const float4* sW4 = (const float4*)(sWt + c * 144);
    #pragma unroll 8
    for (int k4 = 0; k4 < FEAT / 4; ++k4) {
        float4 w  = sW4[k4];
        float4 a0 = *(const float4*)&sX[(rg * 4 + 0) * FEAT + k4 * 4];
        float4 a1 = *(const float4*)&sX[(rg * 4 + 1) * FEAT + k4 * 4];
        float4 a2 = *(const float4*)&sX[(rg * 4 + 2) * FEAT + k4 * 4];
        float4 a3 = *(const float4*)&sX[(rg * 4 + 3) * FEAT + k4 * 4];
        s0 = fmaf(a0.x, w.x, s0); s0 = fmaf(a0.y, w.y, s0); s0 = fmaf(a0.z, w.z, s0); s0 = fmaf(a0.w, w.w, s0);
        s1 = fmaf(a1.x, w.x, s1); s1 = fmaf(a1.y, w.y, s1); s1 = fmaf(a1.z, w.z, s1); s1 = fmaf(a1.w, w.w, s1);
        s2 = fmaf(a2.x, w.x, s2); s2 = fmaf(a2.y, w.y, s2); s2 = fmaf(a2.z, w.z, s2); s2 = fmaf(a2.w, w.w, s2);
        s3 = fmaf(a3.x, w.x, s3); s3 = fmaf(a3.y, w.y, s3); s3 = fmaf(a3.z, w.z, s3); s3 = fmaf(a3.w, w.w, s3);
    }
    float sv[4] = {s0, s1, s2, s3};
    #pragma unroll
    for (int j = 0; j < 4; ++j) {
        int row = row0 + rg * 4 + j;
        if (row < NN) h1h[(long)row * HID + c] = __float2half(sv[j]);
    }
}

// ---- conv1 aggregate: uniform int2 csr loads, fp16 gathers, unroll-8 ----
__global__ __launch_bounds__(256) void k_agg1(const int* __restrict__ row_beg,
                                              const int* __restrict__ row_end,
                                              const int2* __restrict__ csr,
                                              const float* __restrict__ dinv,
                                              const __half* __restrict__ h1h,
                                              const float* __restrict__ b1,
                                              const float* __restrict__ mask,
                                              float* __restrict__ h) {
    int node = blockIdx.x * 4 + (threadIdx.x >> 6);
    if (node >= NN) return;
    int l = threadIdx.x & 63;
    int beg = __builtin_amdgcn_readfirstlane(row_beg[node]);
    int end = __builtin_amdgcn_readfirstlane(row_end[node]);
    float acc = 0.f;
    int j = beg;
    for (; j + 8 <= end; j += 8) {
        int2 e0 = csr[j+0], e1 = csr[j+1], e2 = csr[j+2], e3 = csr[j+3];
        int2 e4 = csr[j+4], e5 = csr[j+5], e6 = csr[j+6], e7 = csr[j+7];
        float a0 = __half2float(h1h[e0.x * HID + l]);
        float a1 = __half2float(h1h[e1.x * HID + l]);
        float a2 = __half2float(h1h[e2.x * HID + l]);
        float a3 = __half2float(h1h[e3.x * HID + l]);
        float a4 = __half2float(h1h[e4.x * HID + l]);
        float a5 = __half2float(h1h[e5.x * HID + l]);
        float a6 = __half2float(h1h[e6.x * HID + l]);
        float a7 = __half2float(h1h[e7.x * HID + l]);
        acc = fmaf(a0, __int_as_float(e0.y), acc);
        acc = fmaf(a1, __int_as_float(e1.y), acc);
        acc = fmaf(a2, __int_as_float(e2.y), acc);
        acc = fmaf(a3, __int_as_float(e3.y), acc);
        acc = fmaf(a4, __int_as_float(e4.y), acc);
        acc = fmaf(a5, __int_as_float(e5.y), acc);
        acc = fmaf(a6, __int_as_float(e6.y), acc);
        acc = fmaf(a7, __int_as_float(e7.y), acc);
    }
    for (; j < end; ++j) {
        int2 e = csr[j];
        acc = fmaf(__half2float(h1h[e.x * HID + l]), __int_as_float(e.y), acc);
    }
    float di = dinv[node];
    float vv = acc + __half2float(h1h[node * HID + l]) * di * di + b1[l];
    vv = vv > 0.f ? vv : 0.f;
    h[node * HID + l] = vv * mask[node * HID + l];
}

// ---- h2h = fp16(h @ W2) : [NN,64] @ [64,40] ----
__global__ __launch_bounds__(320) void k_gemm2(const float* __restrict__ h,
                                               const float* __restrict__ W2,
                                               __half* __restrict__ h2h) {
    __shared__ float sWt[OUTD * 80];      // transposed, stride 80 (2-way banks) 12.8 KB
    __shared__ float sH[32 * HID];        // 8 KB
    int t = threadIdx.x;
    for (int i = t; i < HID * OUTD; i += 320) {
        int k = i / OUTD, c = i - k * OUTD;
        sWt[c * 80 + k] = W2[i];
    }
    int row0 = blockIdx.x * 32;
    const float4* h4 = (const float4*)h;
    float4* sH4 = (float4*)sH;
    for (int i = t; i < 32 * HID / 4; i += 320) {
        int r = row0 + (i >> 4);
        sH4[i] = (r < NN) ? h4[(long)r * (HID / 4) + (i & 15)]
                          : make_float4(0.f, 0.f, 0.f, 0.f);
    }
    __syncthreads();
    int c  = t % OUTD;
    int rg = t / OUTD;                    // 0..7
    float s0 = 0.f, s1 = 0.f, s2 = 0.f, s3 = 0.f;
    const float4* sW4 = (const float4*)(sWt + c * 80);
    #pragma unroll 4
    for (int k4 = 0; k4 < HID / 4; ++k4) {
        float4 w  = sW4[k4];
        float4 a0 = *(const float4*)&sH[(rg * 4 + 0) * HID + k4 * 4];
        float4 a1 = *(const float4*)&sH[(rg * 4 + 1) * HID + k4 * 4];
        float4 a2 = *(const float4*)&sH[(rg * 4 + 2) * HID + k4 * 4];
        float4 a3 = *(const float4*)&sH[(rg * 4 + 3) * HID + k4 * 4];
        s0 = fmaf(a0.x, w.x, s0); s0 = fmaf(a0.y, w.y, s0); s0 = fmaf(a0.z, w.z, s0); s0 = fmaf(a0.w, w.w, s0);
        s1 = fmaf(a1.x, w.x, s1); s1 = fmaf(a1.y, w.y, s1); s1 = fmaf(a1.z, w.z, s1); s1 = fmaf(a1.w, w.w, s1);
        s2 = fmaf(a2.x, w.x, s2); s2 = fmaf(a2.y, w.y, s2); s2 = fmaf(a2.z, w.z, s2); s2 = fmaf(a2.w, w.w, s2);
        s3 = fmaf(a3.x, w.x, s3); s3 = fmaf(a3.y, w.y, s3); s3 = fmaf(a3.z, w.z, s3); s3 = fmaf(a3.w, w.w, s3);
    }
    float sv[4] = {s0, s1, s2, s3};
    #pragma unroll
    for (int j = 0; j < 4; ++j) {
        int row = row0 + rg * 4 + j;
        if (row < NN) h2h[(long)row * OUTD + c] = __float2half(sv[j]);
    }
}

// ---- conv2 aggregate: lanes >= OUTD exit; fp16 gathers, unroll-8 -> out ----
__global__ __launch_bounds__(256) void k_agg2(const int* __restrict__ row_beg,
                                              const int* __restrict__ row_end,
                                              const int2* __restrict__ csr,
                                              const float* __restrict__ dinv,
                                              const __half* __restrict__ h2h,
                                              const float* __restrict__ b2,
                                              float* __restrict__ out) {
    int node = blockIdx.x * 4 + (threadIdx.x >> 6);
    if (node >= NN) return;
    int l = threadIdx.x & 63;
    if (l >= OUTD) return;
    int beg = __builtin_amdgcn_readfirstlane(row_beg[node]);
    int end = __builtin_amdgcn_readfirstlane(row_end[node]);
    float acc = 0.f;
    int j = beg;
    for (; j + 8 <= end; j += 8) {
        int2 e0 = csr[j+0], e1 = csr[j+1], e2 = csr[j+2], e3 = csr[j+3];
        int2 e4 = csr[j+4], e5 = csr[j+5], e6 = csr[j+6], e7 = csr[j+7];
        float a0 = __half2float(h2h[e0.x * OUTD + l]);
        float a1 = __half2float(h2h[e1.x * OUTD + l]);
        float a2 = __half2float(h2h[e2.x * OUTD + l]);
        float a3 = __half2float(h2h[e3.x * OUTD + l]);
        float a4 = __half2float(h2h[e4.x * OUTD + l]);
        float a5 = __half2float(h2h[e5.x * OUTD + l]);
        float a6 = __half2float(h2h[e6.x * OUTD + l]);
        float a7 = __half2float(h2h[e7.x * OUTD + l]);
        acc = fmaf(a0, __int_as_float(e0.y), acc);
        acc = fmaf(a1, __int_as_float(e1.y), acc);
        acc = fmaf(a2, __int_as_float(e2.y), acc);
        acc = fmaf(a3, __int_as_float(e3.y), acc);
        acc = fmaf(a4, __int_as_float(e4.y), acc);
        acc = fmaf(a5, __int_as_float(e5.y), acc);
        acc = fmaf(a6, __int_as_float(e6.y), acc);
        acc = fmaf(a7, __int_as_float(e7.y), acc);
    }
    for (; j < end; ++j) {
        int2 e = csr[j];
        acc = fmaf(__half2float(h2h[e.x * OUTD + l]), __int_as_float(e.y), acc);
    }
    float di = dinv[node];
    out[node * OUTD + l] = acc + __half2float(h2h[node * OUTD + l]) * di * di + b2[l];
}

extern "C" void kernel_launch(void* const* d_in, const int* in_sizes, int n_in,
                              void* d_out, int out_size, void* d_ws, size_t ws_size,
                              hipStream_t stream) {
    const float* x    = (const float*)d_in[0];
    const int*   ei   = (const int*)d_in[1];
    const int*   src  = ei;
    const int*   dst  = ei + NE;
    const float* W1   = (const float*)d_in[2];
    const float* b1   = (const float*)d_in[3];
    const float* W2   = (const float*)d_in[4];
    const float* b2   = (const float*)d_in[5];
    const float* mask = (const float*)d_in[6];
    float* out = (float*)d_out;

    char* ws = (char*)d_ws;
    int*    bfill   = (int*)ws;                ws += (size_t)NBKT * 4;
    int*    row_beg = (int*)ws;                ws += (size_t)NN * 4;
    int*    row_end = (int*)ws;                ws += (size_t)NN * 4;
    float*  dinv    = (float*)ws;              ws += (size_t)NN * 4;
    int2*   csr     = (int2*)ws;               ws += (size_t)NBKT * CAP * 8;   // 16 MB
    __half* h1h     = (__half*)ws;             ws += (size_t)NN * HID * 2;     // 12.8 MB
    float*  h       = (float*)ws;              ws += (size_t)NN * HID * 4;     // 25.6 MB
    int*    pairs   = (int*)h;                 // alias: dead before h written
    __half* h2h     = h1h;                     // alias: h1h dead after k_agg1

    hipMemsetAsync(bfill, 0, (size_t)NBKT * 4, stream);

    k_pairs<<<(NE + CCHUNK - 1) / CCHUNK, 256, 0, stream>>>(src, dst, bfill, pairs);
    k_csr  <<<NBKT, 256, 0, stream>>>(pairs, bfill, row_beg, row_end, dinv, csr);
    k_wts  <<<(NN + 3) / 4, 256, 0, stream>>>(row_beg, row_end, dinv, csr);

    k_gemm1<<<(NN + 15) / 16, 256, 0, stream>>>(x, W1, h1h);
    k_agg1 <<<(NN + 3) / 4, 256, 0, stream>>>(row_beg, row_end, csr, dinv,
                                              h1h, b1, mask, h);
    k_gemm2<<<(NN + 31) / 32, 320, 0, stream>>>(h, W2, h2h);
    k_agg2 <<<(NN + 3) / 4, 256, 0, stream>>>(row_beg, row_end, csr, dinv,
                                              h2h, b2, out);
}

// Round 6
// 205.474 us; speedup vs baseline: 3.9493x; 1.4901x over previous
//
#include <hip/hip_runtime.h>
#include <hip/hip_fp16.h>

#define NN   100000
#define NE   1600000
#define FEAT 128
#define HID  64
#define OUTD 40
#define BSH  8                       // bucket = dst >> 8 (256 nodes/bucket)
#define NBKT ((NN + 255) / 256)      // 391
#define CAP  5120                    // padded bucket capacity (mean 4096, sd 64)
#define CCHUNK 6144                  // edges per block in pair-scatter (mult of 4)

typedef _Float16 half8 __attribute__((ext_vector_type(8)));
typedef float    f32x4 __attribute__((ext_vector_type(4)));

// ---- A. scatter packed (src<<8|dl) into padded bucket segments ----
__global__ __launch_bounds__(256) void k_pairs(const int* __restrict__ src,
                                               const int* __restrict__ dst,
                                               int* __restrict__ bfill,
                                               int* __restrict__ pairs) {
    __shared__ int bcnt[NBKT];
    __shared__ int gb[NBKT];
    for (int i = threadIdx.x; i < NBKT; i += 256) bcnt[i] = 0;
    __syncthreads();
    int e0 = blockIdx.x * CCHUNK;
    int e1 = min(NE, e0 + CCHUNK);
    const int4* d4p = (const int4*)dst;
    const int4* s4p = (const int4*)src;
    for (int q = e0 / 4 + threadIdx.x; q < e1 / 4; q += 256) {
        int4 d4 = d4p[q];
        atomicAdd(&bcnt[d4.x >> BSH], 1);
        atomicAdd(&bcnt[d4.y >> BSH], 1);
        atomicAdd(&bcnt[d4.z >> BSH], 1);
        atomicAdd(&bcnt[d4.w >> BSH], 1);
    }
    __syncthreads();
    for (int i = threadIdx.x; i < NBKT; i += 256) {
        int c = bcnt[i];
        gb[i] = c ? (i * CAP + atomicAdd(&bfill[i], c)) : 0;
        bcnt[i] = 0;
    }
    __syncthreads();
    for (int q = e0 / 4 + threadIdx.x; q < e1 / 4; q += 256) {
        int4 d4 = d4p[q];
        int4 s4 = s4p[q];
        int b, idx;
        b = d4.x >> BSH; idx = gb[b] + atomicAdd(&bcnt[b], 1); pairs[idx] = (s4.x << 8) | (d4.x & 255);
        b = d4.y >> BSH; idx = gb[b] + atomicAdd(&bcnt[b], 1); pairs[idx] = (s4.y << 8) | (d4.y & 255);
        b = d4.z >> BSH; idx = gb[b] + atomicAdd(&bcnt[b], 1); pairs[idx] = (s4.z << 8) | (d4.z & 255);
        b = d4.w >> BSH; idx = gb[b] + atomicAdd(&bcnt[b], 1); pairs[idx] = (s4.w << 8) | (d4.w & 255);
    }
}

// ---- B. per-bucket CSR: row_beg/row_end, dinv, csr.x = src (LDS-local) ----
__global__ __launch_bounds__(256) void k_csr(const int* __restrict__ pairs,
                                             const int* __restrict__ bfill,
                                             int* __restrict__ row_beg,
                                             int* __restrict__ row_end,
                                             float* __restrict__ dinv,
                                             int2* __restrict__ csr) {
    __shared__ int nd[256];
    __shared__ int sc[256];
    __shared__ int ro[257];
    __shared__ int cnt2[256];
    int b = blockIdx.x;
    int t = threadIdx.x;
    int node0 = b << BSH;
    int base  = b * CAP;
    int count = bfill[b];
    nd[t] = 0; cnt2[t] = 0;
    __syncthreads();
    for (int i = t; i < count; i += 256)
        atomicAdd(&nd[pairs[base + i] & 255], 1);
    __syncthreads();
    int v = nd[t];
    sc[t] = v;
    __syncthreads();
    for (int off = 1; off < 256; off <<= 1) {
        int u = (t >= off) ? sc[t - off] : 0;
        __syncthreads();
        sc[t] += u;
        __syncthreads();
    }
    ro[t + 1] = sc[t];
    if (t == 0) ro[0] = 0;
    __syncthreads();
    int node = node0 + t;
    if (node < NN) {
        row_beg[node] = base + ro[t];
        row_end[node] = base + sc[t];
        dinv[node]    = rsqrtf((float)v + 1.0f);
    }
    for (int i = t; i < count; i += 256) {
        int p  = pairs[base + i];
        int dl = p & 255;
        int pos = ro[dl] + atomicAdd(&cnt2[dl], 1);
        csr[base + pos].x = p >> 8;
    }
}

// ---- C. csr.y = bits(dinv[src]*dinv[dst]) ----
__global__ __launch_bounds__(256) void k_wts(const int* __restrict__ row_beg,
                                             const int* __restrict__ row_end,
                                             const float* __restrict__ dinv,
                                             int2* __restrict__ csr) {
    int node = blockIdx.x * 4 + (threadIdx.x >> 6);
    if (node >= NN) return;
    int l = threadIdx.x & 63;
    int beg = row_beg[node], end = row_end[node];
    float di = dinv[node];
    for (int j = beg + l; j < end; j += 64)
        csr[j].y = __float_as_int(dinv[csr[j].x] * di);
}

// ---- D. pack W1/W2 into per-lane MFMA B-fragments (f16) ----
// B-frag layout (16x16x32): lane l holds B[k=(l>>4)*8+i][col=n*16+(l&15)], i=0..7
__global__ __launch_bounds__(256) void k_wprep(const float* __restrict__ W1,
                                               const float* __restrict__ W2,
                                               _Float16* __restrict__ w1f,
                                               _Float16* __restrict__ w2f) {
    int t = threadIdx.x;
    for (int it = t; it < 16 * 64; it += 256) {   // W1: kk 0..3 x n 0..3
        int f = it >> 6, l = it & 63;
        int kk = f >> 2, n = f & 3;
        int krow = kk * 32 + (l >> 4) * 8;
        int col  = n * 16 + (l & 15);
        #pragma unroll
        for (int i = 0; i < 8; ++i)
            w1f[it * 8 + i] = (_Float16)W1[(krow + i) * HID + col];
    }
    for (int it = t; it < 6 * 64; it += 256) {    // W2: kk 0..1 x n 0..2 (cols padded to 48)
        int f = it >> 6, l = it & 63;
        int kk = f / 3, n = f - kk * 3;
        int krow = kk * 32 + (l >> 4) * 8;
        int col  = n * 16 + (l & 15);
        #pragma unroll
        for (int i = 0; i < 8; ++i)
            w2f[it * 8 + i] = (col < OUTD) ? (_Float16)W2[(krow + i) * OUTD + col]
                                           : (_Float16)0.f;
    }
}

// ---- E. h1h = f16(x @ W1) via MFMA: wave = 16 rows x 64 cols ----
__global__ __launch_bounds__(256) void k_mgemm1(const float* __restrict__ x,
                                                const _Float16* __restrict__ w1f,
                                                __half* __restrict__ h1h) {
    int wid = (blockIdx.x * 256 + threadIdx.x) >> 6;   // row-tile id, 6250 total
    int l = threadIdx.x & 63;
    if (wid >= NN / 16) return;
    half8 bf[4][4];
    #pragma unroll
    for (int kk = 0; kk < 4; ++kk)
        #pragma unroll
        for (int n = 0; n < 4; ++n)
            bf[kk][n] = ((const half8*)w1f)[(kk * 4 + n) * 64 + l];
    f32x4 acc[4] = {};
    int arow = wid * 16 + (l & 15);
    const float* xp = x + (size_t)arow * FEAT + (l >> 4) * 8;
    #pragma unroll
    for (int kk = 0; kk < 4; ++kk) {
        float4 u0 = *(const float4*)(xp + kk * 32);
        float4 u1 = *(const float4*)(xp + kk * 32 + 4);
        half8 af;
        af[0] = (_Float16)u0.x; af[1] = (_Float16)u0.y;
        af[2] = (_Float16)u0.z; af[3] = (_Float16)u0.w;
        af[4] = (_Float16)u1.x; af[5] = (_Float16)u1.y;
        af[6] = (_Float16)u1.z; af[7] = (_Float16)u1.w;
        #pragma unroll
        for (int n = 0; n < 4; ++n)
            acc[n] = __builtin_amdgcn_mfma_f32_16x16x32_f16(af, bf[kk][n], acc[n], 0, 0, 0);
    }
    int orow = wid * 16 + (l >> 4) * 4;
    int ocol = l & 15;
    #pragma unroll
    for (int n = 0; n < 4; ++n)
        #pragma unroll
        for (int r = 0; r < 4; ++r)
            h1h[(size_t)(orow + r) * HID + n * 16 + ocol] = __float2half(acc[n][r]);
}

// ---- F. conv1 aggregate: fp16 gathers, unroll-8 -> hh (f16) ----
__global__ __launch_bounds__(256) void k_agg1(const int* __restrict__ row_beg,
                                              const int* __restrict__ row_end,
                                              const int2* __restrict__ csr,
                                              const float* __restrict__ dinv,
                                              const __half* __restrict__ h1h,
                                              const float* __restrict__ b1,
                                              const float* __restrict__ mask,
                                              _Float16* __restrict__ hh) {
    int node = blockIdx.x * 4 + (threadIdx.x >> 6);
    if (node >= NN) return;
    int l = threadIdx.x & 63;
    int beg = __builtin_amdgcn_readfirstlane(row_beg[node]);
    int end = __builtin_amdgcn_readfirstlane(row_end[node]);
    float acc = 0.f;
    int j = beg;
    for (; j + 8 <= end; j += 8) {
        int2 e0 = csr[j+0], e1 = csr[j+1], e2 = csr[j+2], e3 = csr[j+3];
        int2 e4 = csr[j+4], e5 = csr[j+5], e6 = csr[j+6], e7 = csr[j+7];
        float a0 = __half2float(h1h[e0.x * HID + l]);
        float a1 = __half2float(h1h[e1.x * HID + l]);
        float a2 = __half2float(h1h[e2.x * HID + l]);
        float a3 = __half2float(h1h[e3.x * HID + l]);
        float a4 = __half2float(h1h[e4.x * HID + l]);
        float a5 = __half2float(h1h[e5.x * HID + l]);
        float a6 = __half2float(h1h[e6.x * HID + l]);
        float a7 = __half2float(h1h[e7.x * HID + l]);
        acc = fmaf(a0, __int_as_float(e0.y), acc);
        acc = fmaf(a1, __int_as_float(e1.y), acc);
        acc = fmaf(a2, __int_as_float(e2.y), acc);
        acc = fmaf(a3, __int_as_float(e3.y), acc);
        acc = fmaf(a4, __int_as_float(e4.y), acc);
        acc = fmaf(a5, __int_as_float(e5.y), acc);
        acc = fmaf(a6, __int_as_float(e6.y), acc);
        acc = fmaf(a7, __int_as_float(e7.y), acc);
    }
    for (; j < end; ++j) {
        int2 e = csr[j];
        acc = fmaf(__half2float(h1h[e.x * HID + l]), __int_as_float(e.y), acc);
    }
    float di = dinv[node];
    float vv = acc + __half2float(h1h[node * HID + l]) * di * di + b1[l];
    vv = vv > 0.f ? vv : 0.f;
    hh[node * HID + l] = (_Float16)(vv * mask[node * HID + l]);
}

// ---- G. h2h = f16(hh @ W2) via MFMA: wave = 16 rows x 48(->40) cols ----
__global__ __launch_bounds__(256) void k_mgemm2(const _Float16* __restrict__ hh,
                                                const _Float16* __restrict__ w2f,
                                                __half* __restrict__ h2h) {
    int wid = (blockIdx.x * 256 + threadIdx.x) >> 6;
    int l = threadIdx.x & 63;
    if (wid >= NN / 16) return;
    half8 bf[2][3];
    #pragma unroll
    for (int kk = 0; kk < 2; ++kk)
        #pragma unroll
        for (int n = 0; n < 3; ++n)
            bf[kk][n] = ((const half8*)w2f)[(kk * 3 + n) * 64 + l];
    f32x4 acc[3] = {};
    int arow = wid * 16 + (l & 15);
    const _Float16* hp = hh + (size_t)arow * HID + (l >> 4) * 8;
    #pragma unroll
    for (int kk = 0; kk < 2; ++kk) {
        half8 af = *(const half8*)(hp + kk * 32);
        #pragma unroll
        for (int n = 0; n < 3; ++n)
            acc[n] = __builtin_amdgcn_mfma_f32_16x16x32_f16(af, bf[kk][n], acc[n], 0, 0, 0);
    }
    int orow = wid * 16 + (l >> 4) * 4;
    int ocol = l & 15;
    #pragma unroll
    for (int n = 0; n < 3; ++n) {
        int col = n * 16 + ocol;
        if (col < OUTD) {
            #pragma unroll
            for (int r = 0; r < 4; ++r)
                h2h[(size_t)(orow + r) * OUTD + col] = __float2half(acc[n][r]);
        }
    }
}

// ---- H. conv2 aggregate: lanes >= OUTD exit; fp16 gathers, unroll-8 -> out ----
__global__ __launch_bounds__(256) void k_agg2(const int* __restrict__ row_beg,
                                              const int* __restrict__ row_end,
                                              const int2* __restrict__ csr,
                                              const float* __restrict__ dinv,
                                              const __half* __restrict__ h2h,
                                              const float* __restrict__ b2,
                                              float* __restrict__ out) {
    int node = blockIdx.x * 4 + (threadIdx.x >> 6);
    if (node >= NN) return;
    int l = threadIdx.x & 63;
    if (l >= OUTD) return;
    int beg = __builtin_amdgcn_readfirstlane(row_beg[node]);
    int end = __builtin_amdgcn_readfirstlane(row_end[node]);
    float acc = 0.f;
    int j = beg;
    for (; j + 8 <= end; j += 8) {
        int2 e0 = csr[j+0], e1 = csr[j+1], e2 = csr[j+2], e3 = csr[j+3];
        int2 e4 = csr[j+4], e5 = csr[j+5], e6 = csr[j+6], e7 = csr[j+7];
        float a0 = __half2float(h2h[e0.x * OUTD + l]);
        float a1 = __half2float(h2h[e1.x * OUTD + l]);
        float a2 = __half2float(h2h[e2.x * OUTD + l]);
        float a3 = __half2float(h2h[e3.x * OUTD + l]);
        float a4 = __half2float(h2h[e4.x * OUTD + l]);
        float a5 = __half2float(h2h[e5.x * OUTD + l]);
        float a6 = __half2float(h2h[e6.x * OUTD + l]);
        float a7 = __half2float(h2h[e7.x * OUTD + l]);
        acc = fmaf(a0, __int_as_float(e0.y), acc);
        acc = fmaf(a1, __int_as_float(e1.y), acc);
        acc = fmaf(a2, __int_as_float(e2.y), acc);
        acc = fmaf(a3, __int_as_float(e3.y), acc);
        acc = fmaf(a4, __int_as_float(e4.y), acc);
        acc = fmaf(a5, __int_as_float(e5.y), acc);
        acc = fmaf(a6, __int_as_float(e6.y), acc);
        acc = fmaf(a7, __int_as_float(e7.y), acc);
    }
    for (; j < end; ++j) {
        int2 e = csr[j];
        acc = fmaf(__half2float(h2h[e.x * OUTD + l]), __int_as_float(e.y), acc);
    }
    float di = dinv[node];
    out[node * OUTD + l] = acc + __half2float(h2h[node * OUTD + l]) * di * di + b2[l];
}

extern "C" void kernel_launch(void* const* d_in, const int* in_sizes, int n_in,
                              void* d_out, int out_size, void* d_ws, size_t ws_size,
                              hipStream_t stream) {
    const float* x    = (const float*)d_in[0];
    const int*   ei   = (const int*)d_in[1];
    const int*   src  = ei;
    const int*   dst  = ei + NE;
    const float* W1   = (const float*)d_in[2];
    const float* b1   = (const float*)d_in[3];
    const float* W2   = (const float*)d_in[4];
    const float* b2   = (const float*)d_in[5];
    const float* mask = (const float*)d_in[6];
    float* out = (float*)d_out;

    char* ws = (char*)d_ws;
    int*      bfill   = (int*)ws;              ws += (size_t)NBKT * 4;
    int*      row_beg = (int*)ws;              ws += (size_t)NN * 4;
    int*      row_end = (int*)ws;              ws += (size_t)NN * 4;
    float*    dinv    = (float*)ws;            ws += (size_t)NN * 4;
    _Float16* w1f     = (_Float16*)ws;         ws += 16 * 64 * 8 * 2;
    _Float16* w2f     = (_Float16*)ws;         ws += 6 * 64 * 8 * 2;
    int2*     csr     = (int2*)ws;             ws += (size_t)NBKT * CAP * 8;   // 16 MB
    __half*   h1h     = (__half*)ws;           ws += (size_t)NN * HID * 2;     // 12.8 MB
    _Float16* hh      = (_Float16*)ws;         ws += (size_t)NN * HID * 2;     // 12.8 MB
    int*      pairs   = (int*)hh;              // alias: pairs (8 MB) dead before hh written
    __half*   h2h     = h1h;                   // alias: h1h dead after k_agg1

    hipMemsetAsync(bfill, 0, (size_t)NBKT * 4, stream);

    k_pairs <<<(NE + CCHUNK - 1) / CCHUNK, 256, 0, stream>>>(src, dst, bfill, pairs);
    k_csr   <<<NBKT, 256, 0, stream>>>(pairs, bfill, row_beg, row_end, dinv, csr);
    k_wts   <<<(NN + 3) / 4, 256, 0, stream>>>(row_beg, row_end, dinv, csr);
    k_wprep <<<1, 256, 0, stream>>>(W1, W2, w1f, w2f);

    k_mgemm1<<<(NN / 16 + 3) / 4, 256, 0, stream>>>(x, w1f, h1h);
    k_agg1  <<<(NN + 3) / 4, 256, 0, stream>>>(row_beg, row_end, csr, dinv,
                                               h1h, b1, mask, hh);
    k_mgemm2<<<(NN / 16 + 3) / 4, 256, 0, stream>>>(hh, w2f, h2h);
    k_agg2  <<<(NN + 3) / 4, 256, 0, stream>>>(row_beg, row_end, csr, dinv,
                                               h2h, b2, out);
}